// Round 24
// baseline (83.029 us; speedup 1.0000x reference)
//
#include <hip/hip_runtime.h>
#include <hip/hip_fp8.h>

#define N_ROWS 4096
#define D_K    2048
#define BP   128                      // panel size
#define NPAN (N_ROWS / BP)            // 32 panels
#define NTRI (NPAN * (NPAN + 1) / 2)  // 528 triangle tiles
#define BK   64                       // fp8: 64 B per row per K-tile
#define NT   (D_K / BK)               // 32 K-tiles
#define MARGIN 0.3f

typedef unsigned char u8;
typedef __attribute__((ext_vector_type(4))) float f32x4;

__device__ __forceinline__ void stage16(const void* src, void* dst) {
    __builtin_amdgcn_global_load_lds((const __attribute__((address_space(1))) unsigned int*)src,
                                     (__attribute__((address_space(3))) unsigned int*)dst, 16, 0, 0);
}

// ---------- Kernel 1: fp32 -> fp8 e4m3 convert, exact fp32 row norms, init ap2/an2 ----------
__global__ __launch_bounds__(256) void prep_kernel(
    const float* __restrict__ emb, u8* __restrict__ emb8,
    float* __restrict__ xx, unsigned* __restrict__ ap2, unsigned* __restrict__ an2)
{
    const int row = blockIdx.x;
    const int t = threadIdx.x;
    const float4* src = (const float4*)(emb + (size_t)row * D_K);
    float4 v0 = src[2 * t], v1 = src[2 * t + 1];
    float s = 0.f;
    s = fmaf(v0.x, v0.x, s); s = fmaf(v0.y, v0.y, s);
    s = fmaf(v0.z, v0.z, s); s = fmaf(v0.w, v0.w, s);
    s = fmaf(v1.x, v1.x, s); s = fmaf(v1.y, v1.y, s);
    s = fmaf(v1.z, v1.z, s); s = fmaf(v1.w, v1.w, s);
    unsigned lo = 0, hi = 0;
    lo |= (unsigned)__hip_fp8_e4m3(v0.x).__x;
    lo |= (unsigned)__hip_fp8_e4m3(v0.y).__x << 8;
    lo |= (unsigned)__hip_fp8_e4m3(v0.z).__x << 16;
    lo |= (unsigned)__hip_fp8_e4m3(v0.w).__x << 24;
    hi |= (unsigned)__hip_fp8_e4m3(v1.x).__x;
    hi |= (unsigned)__hip_fp8_e4m3(v1.y).__x << 8;
    hi |= (unsigned)__hip_fp8_e4m3(v1.z).__x << 16;
    hi |= (unsigned)__hip_fp8_e4m3(v1.w).__x << 24;
    ((uint2*)(emb8 + (size_t)row * D_K))[t] = make_uint2(lo, hi);
#pragma unroll
    for (int off = 32; off >= 1; off >>= 1) s += __shfl_down(s, off, 64);
    __shared__ float red[4];
    if ((t & 63) == 0) red[t >> 6] = s;
    __syncthreads();
    if (t == 0) {
        xx[row] = red[0] + red[1] + red[2] + red[3];
        ap2[row] = 0u;            // float 0.0
        an2[row] = 0x7f7fffffu;   // FLT_MAX
    }
}

// ---------- Kernel 2: triangle 128x128, fp8 BK=64, r11 engine (32 regions), dual-reduction ----------
__global__ __launch_bounds__(256) void gram_tri_kernel(
    const u8* __restrict__ emb8, const float* __restrict__ xx,
    const int* __restrict__ lab, unsigned* __restrict__ ap2, unsigned* __restrict__ an2)
{
    __shared__ u8 As[BP * BK];    // 8 KiB: [128 rows][64 B], 16B-slot swizzled
    __shared__ u8 Bs[BP * BK];    // 8 KiB
    __shared__ int labR[BP], labC[BP];
    __shared__ float xxR[BP], xxC[BP];

    const int tid = threadIdx.x;

    // XCD-aware bijective swizzle (528 = 66 * 8), then triangle unrank (I <= J)
    const int bid = blockIdx.x;
    const int p = (bid & 7) * (NTRI / 8) + (bid >> 3);
    int I = 0, rem = p;
    while (rem >= NPAN - I) { rem -= NPAN - I; ++I; }
    const int J = I + rem;
    const int row0 = I * BP, col0 = J * BP;
    const bool diag = (I == J);

    // ---- staging: linear LDS dest (tid*16B), pre-swizzled global source.
    // Row = 64B = 4 slots of 16B; involution: slot ^= (row>>1)&3  (r11-verified geometry)
    const int csw = ((tid & 3) ^ ((tid >> 3) & 3)) * 16;  // BYTES
    const int srow = tid >> 2;                            // 0..63
    const u8* gA0 = emb8 + (size_t)(row0 + srow) * D_K + csw;
    const u8* gA1 = emb8 + (size_t)(row0 + 64 + srow) * D_K + csw;
    const u8* gB0 = emb8 + (size_t)(col0 + srow) * D_K + csw;
    const u8* gB1 = emb8 + (size_t)(col0 + 64 + srow) * D_K + csw;
    u8* lA = As + tid * 16;
    u8* lB = Bs + tid * 16;

    // ---- fragment constants: 2x2 waves, wave (wr,wc) owns rows wr*64+.., cols wc*64+..
    // fp8 16x16x32 frag: lane holds 8 bytes, k-chunk fkb (8B); BK=64 = 2 k-slots (32B each).
    const int l = tid & 63, w = tid >> 6;
    const int wr = w >> 1, wc = w & 1;
    const int fr = l & 15, fkb = l >> 4;            // frag row / 8B k-chunk (0..3)
    // 16B slot of chunk (ks=0): fkb>>1; swizzled; sub-8B offset = (fkb&1)*8
    const int kx0 = (((fkb >> 1) ^ ((fr >> 1) & 3)) * 16) + (fkb & 1) * 8;
    const int kx1 = kx0 ^ 32;                       // ks=1: slot^2 -> byte^32
    const char* AB = (const char*)As;
    const char* BB = (const char*)Bs;
    const int aOff = wr * 4096 + fr * 64;           // + m*1024 (bytes)
    const int bOff = wc * 4096 + fr * 64;           // + n*1024 (bytes)

    f32x4 acc[4][4];
#pragma unroll
    for (int m = 0; m < 4; ++m)
#pragma unroll
        for (int n = 0; n < 4; ++n) acc[m][n] = (f32x4){0.f, 0.f, 0.f, 0.f};

    // ---- r11-style K-loop (32 regions): stage -> sync -> read frags + 32 MFMA -> sync
    for (int kt = 0; kt < NT; ++kt) {
        const int ko = kt * BK;   // byte offset
        stage16(gA0 + ko, lA); stage16(gA1 + ko, lA + 4096);
        stage16(gB0 + ko, lB); stage16(gB1 + ko, lB + 4096);
        __syncthreads();
        long aq[4][2], bq[4][2];
#pragma unroll
        for (int m = 0; m < 4; ++m) {
            aq[m][0] = *(const long*)(AB + aOff + m * 1024 + kx0);
            aq[m][1] = *(const long*)(AB + aOff + m * 1024 + kx1);
        }
#pragma unroll
        for (int n = 0; n < 4; ++n) {
            bq[n][0] = *(const long*)(BB + bOff + n * 1024 + kx0);
            bq[n][1] = *(const long*)(BB + bOff + n * 1024 + kx1);
        }
#pragma unroll
        for (int ks = 0; ks < 2; ++ks)
#pragma unroll
            for (int m = 0; m < 4; ++m)
#pragma unroll
                for (int n = 0; n < 4; ++n)
                    acc[m][n] = __builtin_amdgcn_mfma_f32_16x16x32_fp8_fp8(aq[m][ks], bq[n][ks], acc[m][n], 0, 0, 0);
        __syncthreads();
    }

    // ---- epilogue metadata
    if (tid < BP)      { labR[tid] = lab[row0 + tid]; xxR[tid] = xx[row0 + tid]; }
    else               { int u2 = tid - BP; labC[u2] = lab[col0 + u2]; xxC[u2] = xx[col0 + u2]; }
    __syncthreads();

    const int rgrp = l >> 4;

    // ---- ROW pass: output rows = panel I; reduce over this tile's 128 cols
    // C/D layout (dtype-independent): row = m*16 + rgrp*4 + r (+wr*64), col = n*16 + fr (+wc*64)
#pragma unroll
    for (int m = 0; m < 4; ++m) {
#pragma unroll
        for (int r = 0; r < 4; ++r) {
            const int il = wr * 64 + m * 16 + rgrp * 4 + r;
            const int li = labR[il];
            const float xi = xxR[il];
            float apv = 0.f, anv = __FLT_MAX__;
#pragma unroll
            for (int n = 0; n < 4; ++n) {
                const int jl = wc * 64 + n * 16 + fr;
                float d2 = xi + xxC[jl] - 2.f * acc[m][n][r];
                d2 = fmaxf(d2, 1e-12f);
                const bool same = (labC[jl] == li);
                apv = same ? fmaxf(apv, d2) : apv;
                anv = same ? anv : fminf(anv, d2);
            }
#pragma unroll
            for (int off = 1; off < 16; off <<= 1) {   // fold 16 fr-lanes (in-group)
                apv = fmaxf(apv, __shfl_xor(apv, off, 64));
                anv = fminf(anv, __shfl_xor(anv, off, 64));
            }
            if (fr == 0) {
                atomicMax(&ap2[row0 + il], __float_as_uint(apv));
                atomicMin(&an2[row0 + il], __float_as_uint(anv));
            }
        }
    }

    // ---- COL pass (off-diagonal tiles only): output rows = panel J; reduce over tile's 128 rows
    if (!diag) {
#pragma unroll
        for (int n = 0; n < 4; ++n) {
            const int jl = wc * 64 + n * 16 + fr;
            const int lj = labC[jl];
            const float xj = xxC[jl];
            float apv = 0.f, anv = __FLT_MAX__;
#pragma unroll
            for (int m = 0; m < 4; ++m) {
#pragma unroll
                for (int r = 0; r < 4; ++r) {
                    const int il = wr * 64 + m * 16 + rgrp * 4 + r;
                    float d2 = xj + xxR[il] - 2.f * acc[m][n][r];
                    d2 = fmaxf(d2, 1e-12f);
                    const bool same = (labR[il] == lj);
                    apv = same ? fmaxf(apv, d2) : apv;
                    anv = same ? anv : fminf(anv, d2);
                }
            }
            // fold rgrp groups (lanes differ in bits 4-5; fr/col preserved)
            apv = fmaxf(apv, __shfl_xor(apv, 16, 64));
            anv = fminf(anv, __shfl_xor(anv, 16, 64));
            apv = fmaxf(apv, __shfl_xor(apv, 32, 64));
            anv = fminf(anv, __shfl_xor(anv, 32, 64));
            if (rgrp == 0) {   // one lane per col per wave; both wr waves merge via atomics
                atomicMax(&ap2[col0 + jl], __float_as_uint(apv));
                atomicMin(&an2[col0 + jl], __float_as_uint(anv));
            }
        }
    }
}

// ---------- Kernel 3: finalize loss + precision ----------
__global__ __launch_bounds__(256) void finalize_kernel(
    const unsigned* __restrict__ ap2, const unsigned* __restrict__ an2, float* __restrict__ out)
{
    const int t = threadIdx.x;
    float ls = 0.f, ps = 0.f;
    for (int i = t; i < N_ROWS; i += 256) {
        const float ap = sqrtf(__uint_as_float(ap2[i]));
        const float an = sqrtf(__uint_as_float(an2[i]));
        ls += fmaxf(MARGIN - an + ap, 0.f);
        ps += (an > ap) ? 1.f : 0.f;
    }
#pragma unroll
    for (int off = 32; off >= 1; off >>= 1) {
        ls += __shfl_down(ls, off, 64);
        ps += __shfl_down(ps, off, 64);
    }
    __shared__ float rl[4], rp[4];
    if ((t & 63) == 0) { rl[t >> 6] = ls; rp[t >> 6] = ps; }
    __syncthreads();
    if (t == 0) {
        out[0] = (rl[0] + rl[1] + rl[2] + rl[3]) * (1.f / N_ROWS);
        out[1] = (rp[0] + rp[1] + rp[2] + rp[3]) * (1.f / N_ROWS);
    }
}

extern "C" void kernel_launch(void* const* d_in, const int* in_sizes, int n_in,
                              void* d_out, int out_size, void* d_ws, size_t ws_size,
                              hipStream_t stream)
{
    const float* emb = (const float*)d_in[0];
    const int* lab = (const int*)d_in[1];
    float* out = (float*)d_out;

    char* ws = (char*)d_ws;
    u8* emb8    = (u8*)ws;                                            // 8 MB
    float* xx   = (float*)(ws + (size_t)N_ROWS * D_K);
    unsigned* ap2 = (unsigned*)(ws + (size_t)N_ROWS * D_K + N_ROWS * 4);
    unsigned* an2 = (unsigned*)(ws + (size_t)N_ROWS * D_K + 2 * (size_t)N_ROWS * 4);

    prep_kernel<<<N_ROWS, 256, 0, stream>>>(emb, emb8, xx, ap2, an2);
    gram_tri_kernel<<<NTRI, 256, 0, stream>>>(emb8, xx, lab, ap2, an2);   // 528 blocks
    finalize_kernel<<<1, 256, 0, stream>>>(ap2, an2, out);
}

// Round 25
// 74.704 us; speedup vs baseline: 1.1114x; 1.1114x over previous
//
#include <hip/hip_runtime.h>
#include <hip/hip_fp8.h>

#define N_ROWS 4096
#define D_K    2048
#define BP   128                      // panel size
#define NPAN (N_ROWS / BP)            // 32 panels
#define NTRI (NPAN * (NPAN + 1) / 2)  // 528 triangle tiles
#define BK   64                       // fp8: 64 B per row per K-tile
#define NT   (D_K / BK)               // 32 K-tiles
#define MARGIN 0.3f

typedef unsigned char u8;
typedef __attribute__((ext_vector_type(4))) float f32x4;

__device__ __forceinline__ void stage16(const void* src, void* dst) {
    __builtin_amdgcn_global_load_lds((const __attribute__((address_space(1))) unsigned int*)src,
                                     (__attribute__((address_space(3))) unsigned int*)dst, 16, 0, 0);
}

// ---------- Kernel 1: fp32 -> fp8 e4m3 (K-chunk-paired layout), exact norms, init ----------
// Within each 64B row-group, 8B chunks are stored as [c0 c4 c1 c5 c2 c6 c3 c7]:
// chunk lc -> position (lc<4 ? 2*lc : 2*(lc-4)+1). Applied identically to all rows,
// so A/B MFMA operands always pair matching K-chunks (dot product invariant).
__global__ __launch_bounds__(256) void prep_kernel(
    const float* __restrict__ emb, u8* __restrict__ emb8,
    float* __restrict__ xx, unsigned* __restrict__ ap2, unsigned* __restrict__ an2)
{
    const int row = blockIdx.x;
    const int t = threadIdx.x;
    const float4* src = (const float4*)(emb + (size_t)row * D_K);
    float4 v0 = src[2 * t], v1 = src[2 * t + 1];
    float s = 0.f;
    s = fmaf(v0.x, v0.x, s); s = fmaf(v0.y, v0.y, s);
    s = fmaf(v0.z, v0.z, s); s = fmaf(v0.w, v0.w, s);
    s = fmaf(v1.x, v1.x, s); s = fmaf(v1.y, v1.y, s);
    s = fmaf(v1.z, v1.z, s); s = fmaf(v1.w, v1.w, s);
    unsigned lo = 0, hi = 0;
    lo |= (unsigned)__hip_fp8_e4m3(v0.x).__x;
    lo |= (unsigned)__hip_fp8_e4m3(v0.y).__x << 8;
    lo |= (unsigned)__hip_fp8_e4m3(v0.z).__x << 16;
    lo |= (unsigned)__hip_fp8_e4m3(v0.w).__x << 24;
    hi |= (unsigned)__hip_fp8_e4m3(v1.x).__x;
    hi |= (unsigned)__hip_fp8_e4m3(v1.y).__x << 8;
    hi |= (unsigned)__hip_fp8_e4m3(v1.z).__x << 16;
    hi |= (unsigned)__hip_fp8_e4m3(v1.w).__x << 24;
    // thread t produced global chunk t (8 bytes); permute within its 64B group
    const int g = t >> 3, lc = t & 7;
    const int np = (lc < 4) ? (2 * lc) : (2 * (lc - 4) + 1);
    *(uint2*)(emb8 + (size_t)row * D_K + g * 64 + np * 8) = make_uint2(lo, hi);
#pragma unroll
    for (int off = 32; off >= 1; off >>= 1) s += __shfl_down(s, off, 64);
    __shared__ float red[4];
    if ((t & 63) == 0) red[t >> 6] = s;
    __syncthreads();
    if (t == 0) {
        xx[row] = red[0] + red[1] + red[2] + red[3];
        ap2[row] = 0u;            // float 0.0
        an2[row] = 0x7f7fffffu;   // FLT_MAX
    }
}

// ---------- Kernel 2: triangle 128x128, fp8 BK=64, r11 read geometry, dual-reduction ----------
__global__ __launch_bounds__(256) void gram_tri_kernel(
    const u8* __restrict__ emb8, const float* __restrict__ xx,
    const int* __restrict__ lab, unsigned* __restrict__ ap2, unsigned* __restrict__ an2)
{
    __shared__ u8 As[BP * BK];    // 8 KiB: [128 rows][64 B], 16B-slot swizzled
    __shared__ u8 Bs[BP * BK];    // 8 KiB
    __shared__ int labR[BP], labC[BP];
    __shared__ float xxR[BP], xxC[BP];

    const int tid = threadIdx.x;

    // XCD-aware bijective swizzle (528 = 66 * 8), then triangle unrank (I <= J)
    const int bid = blockIdx.x;
    const int p = (bid & 7) * (NTRI / 8) + (bid >> 3);
    int I = 0, rem = p;
    while (rem >= NPAN - I) { rem -= NPAN - I; ++I; }
    const int J = I + rem;
    const int row0 = I * BP, col0 = J * BP;
    const bool diag = (I == J);

    // ---- staging: linear LDS dest (tid*16B), pre-swizzled global source.
    // Row = 64B = 4 slots of 16B; involution: slot ^= (row>>1)&3  (r11-verified, 0 conflicts)
    const int csw = ((tid & 3) ^ ((tid >> 3) & 3)) * 16;  // BYTES
    const int srow = tid >> 2;                            // 0..63
    const u8* gA0 = emb8 + (size_t)(row0 + srow) * D_K + csw;
    const u8* gA1 = emb8 + (size_t)(row0 + 64 + srow) * D_K + csw;
    const u8* gB0 = emb8 + (size_t)(col0 + srow) * D_K + csw;
    const u8* gB1 = emb8 + (size_t)(col0 + 64 + srow) * D_K + csw;
    u8* lA = As + tid * 16;
    u8* lB = Bs + tid * 16;

    // ---- fragment constants: 2x2 waves, wave (wr,wc) owns rows wr*64+.., cols wc*64+..
    // Paired layout: 16B slot fkb of a row = [chunk fkb (ks0) | chunk fkb+4 (ks1)].
    // Read geometry identical to r11 bf16: slot = fkb ^ ((fr>>1)&3), one b128 per frag.
    const int l = tid & 63, w = tid >> 6;
    const int wr = w >> 1, wc = w & 1;
    const int fr = l & 15, fkb = l >> 4;            // frag row / k-chunk (0..3)
    const int kx = (fkb ^ ((fr >> 1) & 3)) * 16;    // swizzled 16B slot (bytes)
    const char* AB = (const char*)As;
    const char* BB = (const char*)Bs;
    const int aOff = wr * 4096 + fr * 64;           // + m*1024 (bytes)
    const int bOff = wc * 4096 + fr * 64;           // + n*1024 (bytes)

    f32x4 acc[4][4];
#pragma unroll
    for (int m = 0; m < 4; ++m)
#pragma unroll
        for (int n = 0; n < 4; ++n) acc[m][n] = (f32x4){0.f, 0.f, 0.f, 0.f};

    // ---- r11-style K-loop (32 regions): stage -> sync -> 8x b128 reads + 32 MFMA -> sync
    for (int kt = 0; kt < NT; ++kt) {
        const int ko = kt * BK;   // byte offset
        stage16(gA0 + ko, lA); stage16(gA1 + ko, lA + 4096);
        stage16(gB0 + ko, lB); stage16(gB1 + ko, lB + 4096);
        __syncthreads();
        long a0[4], a1[4], b0[4], b1[4];
#pragma unroll
        for (int m = 0; m < 4; ++m) {
            long2 v = *(const long2*)(AB + aOff + m * 1024 + kx);
            a0[m] = v.x; a1[m] = v.y;
        }
#pragma unroll
        for (int n = 0; n < 4; ++n) {
            long2 v = *(const long2*)(BB + bOff + n * 1024 + kx);
            b0[n] = v.x; b1[n] = v.y;
        }
#pragma unroll
        for (int m = 0; m < 4; ++m)
#pragma unroll
            for (int n = 0; n < 4; ++n) {
                acc[m][n] = __builtin_amdgcn_mfma_f32_16x16x32_fp8_fp8(a0[m], b0[n], acc[m][n], 0, 0, 0);
                acc[m][n] = __builtin_amdgcn_mfma_f32_16x16x32_fp8_fp8(a1[m], b1[n], acc[m][n], 0, 0, 0);
            }
        __syncthreads();
    }

    // ---- epilogue metadata
    if (tid < BP)      { labR[tid] = lab[row0 + tid]; xxR[tid] = xx[row0 + tid]; }
    else               { int u2 = tid - BP; labC[u2] = lab[col0 + u2]; xxC[u2] = xx[col0 + u2]; }
    __syncthreads();

    const int rgrp = l >> 4;

    // ---- ROW pass: output rows = panel I; reduce over this tile's 128 cols
    // C/D layout (dtype-independent): row = m*16 + rgrp*4 + r (+wr*64), col = n*16 + fr (+wc*64)
#pragma unroll
    for (int m = 0; m < 4; ++m) {
#pragma unroll
        for (int r = 0; r < 4; ++r) {
            const int il = wr * 64 + m * 16 + rgrp * 4 + r;
            const int li = labR[il];
            const float xi = xxR[il];
            float apv = 0.f, anv = __FLT_MAX__;
#pragma unroll
            for (int n = 0; n < 4; ++n) {
                const int jl = wc * 64 + n * 16 + fr;
                float d2 = xi + xxC[jl] - 2.f * acc[m][n][r];
                d2 = fmaxf(d2, 1e-12f);
                const bool same = (labC[jl] == li);
                apv = same ? fmaxf(apv, d2) : apv;
                anv = same ? anv : fminf(anv, d2);
            }
#pragma unroll
            for (int off = 1; off < 16; off <<= 1) {   // fold 16 fr-lanes (in-group)
                apv = fmaxf(apv, __shfl_xor(apv, off, 64));
                anv = fminf(anv, __shfl_xor(anv, off, 64));
            }
            if (fr == 0) {
                atomicMax(&ap2[row0 + il], __float_as_uint(apv));
                atomicMin(&an2[row0 + il], __float_as_uint(anv));
            }
        }
    }

    // ---- COL pass (off-diagonal tiles only): output rows = panel J; reduce over tile's 128 rows
    if (!diag) {
#pragma unroll
        for (int n = 0; n < 4; ++n) {
            const int jl = wc * 64 + n * 16 + fr;
            const int lj = labC[jl];
            const float xj = xxC[jl];
            float apv = 0.f, anv = __FLT_MAX__;
#pragma unroll
            for (int m = 0; m < 4; ++m) {
#pragma unroll
                for (int r = 0; r < 4; ++r) {
                    const int il = wr * 64 + m * 16 + rgrp * 4 + r;
                    float d2 = xj + xxR[il] - 2.f * acc[m][n][r];
                    d2 = fmaxf(d2, 1e-12f);
                    const bool same = (labR[il] == lj);
                    apv = same ? fmaxf(apv, d2) : apv;
                    anv = same ? anv : fminf(anv, d2);
                }
            }
            // fold rgrp groups (lanes differ in bits 4-5; fr/col preserved)
            apv = fmaxf(apv, __shfl_xor(apv, 16, 64));
            anv = fminf(anv, __shfl_xor(anv, 16, 64));
            apv = fmaxf(apv, __shfl_xor(apv, 32, 64));
            anv = fminf(anv, __shfl_xor(anv, 32, 64));
            if (rgrp == 0) {   // one lane per col per wave; both wr waves merge via atomics
                atomicMax(&ap2[col0 + jl], __float_as_uint(apv));
                atomicMin(&an2[col0 + jl], __float_as_uint(anv));
            }
        }
    }
}

// ---------- Kernel 3: finalize loss + precision ----------
__global__ __launch_bounds__(256) void finalize_kernel(
    const unsigned* __restrict__ ap2, const unsigned* __restrict__ an2, float* __restrict__ out)
{
    const int t = threadIdx.x;
    float ls = 0.f, ps = 0.f;
    for (int i = t; i < N_ROWS; i += 256) {
        const float ap = sqrtf(__uint_as_float(ap2[i]));
        const float an = sqrtf(__uint_as_float(an2[i]));
        ls += fmaxf(MARGIN - an + ap, 0.f);
        ps += (an > ap) ? 1.f : 0.f;
    }
#pragma unroll
    for (int off = 32; off >= 1; off >>= 1) {
        ls += __shfl_down(ls, off, 64);
        ps += __shfl_down(ps, off, 64);
    }
    __shared__ float rl[4], rp[4];
    if ((t & 63) == 0) { rl[t >> 6] = ls; rp[t >> 6] = ps; }
    __syncthreads();
    if (t == 0) {
        out[0] = (rl[0] + rl[1] + rl[2] + rl[3]) * (1.f / N_ROWS);
        out[1] = (rp[0] + rp[1] + rp[2] + rp[3]) * (1.f / N_ROWS);
    }
}

extern "C" void kernel_launch(void* const* d_in, const int* in_sizes, int n_in,
                              void* d_out, int out_size, void* d_ws, size_t ws_size,
                              hipStream_t stream)
{
    const float* emb = (const float*)d_in[0];
    const int* lab = (const int*)d_in[1];
    float* out = (float*)d_out;

    char* ws = (char*)d_ws;
    u8* emb8    = (u8*)ws;                                            // 8 MB
    float* xx   = (float*)(ws + (size_t)N_ROWS * D_K);
    unsigned* ap2 = (unsigned*)(ws + (size_t)N_ROWS * D_K + N_ROWS * 4);
    unsigned* an2 = (unsigned*)(ws + (size_t)N_ROWS * D_K + 2 * (size_t)N_ROWS * 4);

    prep_kernel<<<N_ROWS, 256, 0, stream>>>(emb, emb8, xx, ap2, an2);
    gram_tri_kernel<<<NTRI, 256, 0, stream>>>(emb8, xx, lab, ap2, an2);   // 528 blocks
    finalize_kernel<<<1, 256, 0, stream>>>(ap2, an2, out);
}